// Round 1
// baseline (185.310 us; speedup 1.0000x reference)
//
#include <hip/hip_runtime.h>
#include <math.h>

// Problem constants (from reference)
#define NA 3
#define NC 80
#define CH 85              // NC+5
#define NB 16
#define HH 52
#define WW 52
#define HW 2704            // HH*WW
#define HWF4 676           // HW/4
#define NT 256             // num targets
#define NCELLS (NB*NA*HW)  // 129792
#define NBMW 4056          // bitmap words = ceil(NCELLS/32)
#define STRIDE_F 8.0f      // 416/52
#define IGN_THR 0.5f

// Tiling (R4 winner): 104 pixels/block (26 float4), 26 chunks x 48 ba.
// R6 change: SINGLE merged kernel. Tail work (winner gather / zero-cell
// corrections / partial sum / finalize) folded in as extra blocks that
// spin on a device-scope flag set by the prep block, overlapping with the
// dense phase instead of serializing behind it in a second launch.
// Control words are zeroed by a 96-B hipMemsetAsync (poisoned-ws safe).
#define TP 104
#define TF4 26
#define NF4 2210           // CH * TF4 f4-elements per tile
#define LSTR 105
#define LDSW 8945          // SW(84,103)+1 words = 35.8 KB -> 4 blk/CU
#define NDENSE 1248        // 26 chunks * 48 (B*A)

// Block-id map: 0 = prep; 1..64 = winner gather (4 winners/blk, 1/wave);
// 65..67 = zero-cell corrections (256 idx/blk, 768 total); 68..1315 =
// dense transform; 1316 = partial-sum (waits for all dense).
#define PREP_BID 0
#define WIN_B0 1
#define NWINB 64
#define ZERO_B0 (WIN_B0 + NWINB)      // 65
#define NZEROB 3
#define DENSE_B0 (ZERO_B0 + NZEROB)   // 68
#define PART_BID (DENSE_B0 + NDENSE)  // 1316
#define GRID (PART_BID + 1)           // 1317
#define NTAILP (NWINB + NZEROB + 1)   // 68 done-counter participants

#define SW(c, l) ((c) * LSTR + (l) + ((c) >> 2))

__device__ __forceinline__ float sigm(float z) { return 1.0f / (1.0f + expf(-z)); }
// -log(sigmoid(z)) = log1p(exp(-z));  -log(1-sigmoid(z)) = log1p(exp(z))
__device__ __forceinline__ float splus(float z) { return log1pf(expf(z)); }

// ws layout (bytes):
//   0    : float acc[16]  acc[0]=dense noobj, acc[1]=obj xywh+conf,
//                         acc[2]=cls, acc[3]=zeroed-cell noobj correction
//   64   : int cnts[8]    {wcount, zcount, dense_done, tail_done, prep_flag}
//   128  : int   wofs[256]
//   1152 : float wtx[256]
//   2176 : float wty[256]
//   3200 : float wtw[256]
//   4224 : float wth[256]
//   5248 : int   wlabel[256]
//   6272 : int   zofs[768]
//   9344 : float partials[1248]
// bytes [0,96) zeroed by hipMemsetAsync before the kernel.

__global__ __launch_bounds__(256) void yolo_fused(
        const float* __restrict__ x, float* __restrict__ out,
        const float* __restrict__ target, float* __restrict__ acc,
        int* __restrict__ cnts, int* __restrict__ wofs,
        float* __restrict__ wtx, float* __restrict__ wty,
        float* __restrict__ wtw, float* __restrict__ wth,
        int* __restrict__ wlabel, int* __restrict__ zofs,
        float* __restrict__ partials, float* __restrict__ out_total) {
    __shared__ float lds[LDSW];        // prep block aliases it (17.3 KB used)
    __shared__ float red[4];
    int bid = blockIdx.x;
    int t = threadIdx.x;

    if (bid == PREP_BID) {
        // ---------------- prep block ----------------
        unsigned int* bm = (unsigned int*)lds;          // [NBMW]
        int* s_keyobj = (int*)lds + NBMW;               // [256]
        int* s_cnt = (int*)lds + NBMW + NT;             // {wcnt, zcnt}
        if (t == 0) { s_cnt[0] = 0; s_cnt[1] = 0; }
        for (int i = t; i < NBMW; i += 256) bm[i] = 0u;

        const float awc[3] = {10.f, 16.f, 33.f};
        const float ahc[3] = {13.f, 30.f, 23.f};
        float timg = target[t*6 + 0];
        float gxc  = target[t*6 + 1] * (float)WW;
        float gyc  = target[t*6 + 2] * (float)HH;
        float gw   = target[t*6 + 3] * (float)WW;
        float gh   = target[t*6 + 4] * (float)HH;
        int label  = (int)target[t*6 + 5];

        float best_iou = -1.0f;
        int best = 0, ignbits = 0;
        for (int a = 0; a < 3; a++) {
            float inter = fminf(awc[a], gw) * fminf(ahc[a], gh);
            float iou = inter / (awc[a]*ahc[a] + 1e-16f + gw*gh - inter);
            if (iou > best_iou) { best_iou = iou; best = a; }  // first-max
            if (iou > IGN_THR) ignbits |= (1 << a);
        }
        int img = (int)timg;
        int gi = (int)gxc, gj = (int)gyc;
        int pixel = gj * WW + gi;
        int cellbase = img * (NA * HW) + pixel;
        int keyobj = cellbase + best * HW;
        s_keyobj[t] = keyobj;
        __syncthreads();

        // winner iff no later target maps to same cell (fixed-trip scan)
        bool dup = false;
        #pragma unroll 8
        for (int m = 0; m < NT; m++) {
            int k = s_keyobj[m];
            dup = dup || (m > t && k == keyobj);
        }
        if (!dup) {
            int p = atomicAdd(&s_cnt[0], 1);
            wofs[p] = (img * NA + best) * (CH * HW) + pixel;
            wtx[p] = gxc - floorf(gxc);
            wty[p] = gyc - floorf(gyc);
            wtw[p] = logf(gw / awc[best] + 1e-16f);
            wth[p] = logf(gh / ahc[best] + 1e-16f);
            wlabel[p] = label;
        }
        // distinct zeroed-noobj cells via bitmap (first setter appends)
        for (int a = 0; a < 3; a++) {
            bool flag = (a == best) || ((ignbits >> a) & 1);
            if (flag) {
                int key = cellbase + a * HW;
                unsigned int bit = 1u << (key & 31);
                unsigned int old = atomicOr(&bm[key >> 5], bit);
                if (!(old & bit)) {
                    int p = atomicAdd(&s_cnt[1], 1);
                    zofs[p] = ((img * NA + a) * CH + 4) * HW + pixel;
                }
            }
        }
        __threadfence();               // release each thread's table writes
        __syncthreads();
        if (t == 0) {
            cnts[0] = s_cnt[0]; cnts[1] = s_cnt[1];
            __threadfence();
            atomicExch(&cnts[4], 1);   // publish: prep data ready
        }
        return;
    }

    if (bid >= DENSE_B0 && bid < PART_BID) {
        // ---------------- dense transform block ----------------
        int dbid  = bid - DENSE_B0;
        int chunk = dbid % 26;           // pixel chunk (104 px = 2 grid rows)
        int ba    = dbid / 26;           // b*3 + a
        int a     = ba % NA;
        const float awc[3] = {10.f, 16.f, 33.f};
        const float ahc[3] = {13.f, 30.f, 23.f};

        // Phase 1: batched float4 loads, then transform -> swizzled LDS
        const float4* x4 = (const float4*)x + (size_t)ba * (CH * HWF4)
                                            + chunk * TF4;
        float4 v[9];
        #pragma unroll
        for (int i = 0; i < 9; i++) {
            int idx = t + i * 256;
            if (idx < NF4) {
                int c = idx / TF4, q = idx - c * TF4;
                v[i] = x4[c * HWF4 + q];
            }
        }
        float noobj = 0.0f;
        #pragma unroll
        for (int i = 0; i < 9; i++) {
            int idx = t + i * 256;
            if (idx < NF4) {
                int c = idx / TF4, q = idx - c * TF4;
                float r[4] = {v[i].x, v[i].y, v[i].z, v[i].w};
                #pragma unroll
                for (int k = 0; k < 4; k++) {
                    int l = q * 4 + k;               // local pixel 0..103
                    float z = r[k], o;
                    if (c == 0) {
                        int wc = l - ((l >= WW) ? WW : 0);
                        o = (sigm(z) + (float)wc) * STRIDE_F;
                    } else if (c == 1) {
                        int hc = chunk * 2 + ((l >= WW) ? 1 : 0);
                        o = (sigm(z) + (float)hc) * STRIDE_F;
                    } else if (c == 2) {
                        o = expf(z) * awc[a];
                    } else if (c == 3) {
                        o = expf(z) * ahc[a];
                    } else {
                        o = sigm(z);
                        if (c == 4) noobj += splus(z);
                    }
                    lds[SW(c, l)] = o;
                }
            }
        }
        // reduce noobj partial across the block
        for (int off = 32; off > 0; off >>= 1)
            noobj += __shfl_down(noobj, off, 64);
        if ((t & 63) == 0) red[t >> 6] = noobj;
        __syncthreads();

        // Phase 2: float4 stores of [cell][channel]-ordered output
        float4* o4 = (float4*)out + (size_t)ba * (HW * CH / 4) + chunk * NF4;
        #pragma unroll
        for (int i = 0; i < 9; i++) {
            int j = t + i * 256;
            if (j < NF4) {
                int flat = 4 * j;
                int cell = flat / CH;            // local cell 0..103
                int ch = flat - cell * CH;
                float4 w;
                float* pw = &w.x;
                #pragma unroll
                for (int k = 0; k < 4; k++) {
                    int chk = ch + k, cek = cell;
                    if (chk >= CH) { chk -= CH; cek += 1; }
                    pw[k] = lds[SW(chk, cek)];
                }
                o4[j] = w;
            }
        }
        if (t == 0) {
            partials[dbid] = red[0] + red[1] + red[2] + red[3];
            __threadfence();               // release partials write
            atomicAdd(&cnts[2], 1);        // dense_done++
        }
        return;
    }

    // ---------------- tail participant blocks ----------------
    // winner gather (1..64), zero-cell corrections (65..67), partial (1316)
    if (t == 0) {
        while (atomicAdd(&cnts[4], 0) == 0)            // wait prep publish
            __builtin_amdgcn_s_sleep(8);
        if (bid == PART_BID) {
            while (atomicAdd(&cnts[2], 0) < NDENSE)    // wait all dense
                __builtin_amdgcn_s_sleep(16);
        }
    }
    __syncthreads();
    __threadfence();                        // acquire prep/dense data

    if (bid < ZERO_B0) {
        // ---- winner gather: one winner per 64-lane wave ----
        int wave = t >> 6, lane = t & 63;
        int w = (bid - WIN_B0) * 4 + wave;
        if (w < cnts[0]) {
            int ofs = wofs[w];
            int label = wlabel[w];
            const float* xp = x + ofs;
            float lcls;
            {   // class channels 0..63
                float z = xp[(size_t)(5 + lane) * HW];
                lcls = (lane == label) ? splus(-z) : splus(z);
            }
            if (lane < 16) {               // class channels 64..79
                int c = 64 + lane;
                float z = xp[(size_t)(5 + c) * HW];
                lcls += (c == label) ? splus(-z) : splus(z);
            }
            float other = 0.0f;
            if (lane == 0) {
                float z0 = xp[0];
                float z2 = xp[(size_t)2 * HW];
                float z4 = xp[(size_t)4 * HW];
                float cx = sigm(z0);
                float dx = cx - wtx[w], dy = cx - wty[w];  // ref bug: cx for y
                float dw = z2 - wtw[w], dh = z2 - wth[w];  // ref bug: pw for h
                other = dx*dx + dy*dy + dw*dw + dh*dh + splus(-z4);
            }
            for (int off = 32; off > 0; off >>= 1)
                lcls += __shfl_down(lcls, off, 64);
            if (lane == 0) {
                atomicAdd(&acc[1], other);
                atomicAdd(&acc[2], lcls);
            }
        }
    } else if (bid < DENSE_B0) {
        // ---- zero-cell noobj corrections (768 slots over 3 blocks) ----
        int idx = (bid - ZERO_B0) * 256 + t;
        float v = 0.0f;
        if (idx < cnts[1]) v = splus(x[zofs[idx]]);
        for (int off = 32; off > 0; off >>= 1)
            v += __shfl_down(v, off, 64);
        if ((t & 63) == 0) atomicAdd(&acc[3], v);
    } else {
        // ---- partial-sum block ----
        float s = 0.0f;
        for (int i = t; i < NDENSE; i += 256) s += partials[i];
        for (int off = 32; off > 0; off >>= 1)
            s += __shfl_down(s, off, 64);
        if ((t & 63) == 0) red[t >> 6] = s;
        __syncthreads();
        if (t == 0) atomicAdd(&acc[0], red[0] + red[1] + red[2] + red[3]);
    }

    // ---- last-finishing tail participant finalizes the scalar ----
    __syncthreads();
    __threadfence();                        // release this block's acc adds
    if (t == 0) {
        int old = atomicAdd(&cnts[3], 1);
        if (old == NTAILP - 1) {
            __threadfence();
            float a0 = atomicAdd(&acc[0], 0.0f);   // coherent reads
            float a1 = atomicAdd(&acc[1], 0.0f);
            float a2 = atomicAdd(&acc[2], 0.0f);
            float a3 = atomicAdd(&acc[3], 0.0f);
            float wc = (float)cnts[0];
            float n_obj = fmaxf(wc, 1.0f);
            float n_noobj = fmaxf((float)NCELLS - (float)cnts[1], 1.0f);
            float cls_den = fmaxf(80.0f * wc, 1.0f);
            out_total[0] = a1 / n_obj + a2 / cls_den
                         + 0.5f * ((a0 - a3) / n_noobj);
        }
    }
}

// ---------------------------------------------------------------------------
extern "C" void kernel_launch(void* const* d_in, const int* in_sizes, int n_in,
                              void* d_out, int out_size, void* d_ws, size_t ws_size,
                              hipStream_t stream) {
    (void)in_sizes; (void)n_in; (void)out_size; (void)ws_size;
    const float* x      = (const float*)d_in[0];
    const float* target = (const float*)d_in[1];
    float* out = (float*)d_out;

    char* ws = (char*)d_ws;
    float* acc      = (float*)(ws + 0);
    int*   cnts     = (int*)  (ws + 64);
    int*   wofs     = (int*)  (ws + 128);
    float* wtx      = (float*)(ws + 1152);
    float* wty      = (float*)(ws + 2176);
    float* wtw      = (float*)(ws + 3200);
    float* wth      = (float*)(ws + 4224);
    int*   wlabel   = (int*)  (ws + 5248);
    int*   zofs     = (int*)  (ws + 6272);
    float* partials = (float*)(ws + 9344);

    // zero acc[16] + cnts[8] (workspace is poisoned between iterations)
    hipMemsetAsync(ws, 0, 96, stream);
    yolo_fused<<<GRID, 256, 0, stream>>>(
        x, out, target, acc, cnts, wofs, wtx, wty, wtw, wth, wlabel, zofs,
        partials, out + (size_t)NB * NA * HW * CH);
}

// Round 2
// 162.670 us; speedup vs baseline: 1.1392x; 1.1392x over previous
//
#include <hip/hip_runtime.h>
#include <math.h>

// Problem constants (from reference)
#define NA 3
#define NC 80
#define CH 85              // NC+5
#define NB 16
#define HH 52
#define WW 52
#define HW 2704            // HH*WW
#define HWF4 676           // HW/4
#define NT 256             // num targets
#define NCELLS (NB*NA*HW)  // 129792
#define NBMW 4056          // bitmap words = ceil(NCELLS/32)
#define STRIDE_F 8.0f      // 416/52
#define IGN_THR 0.5f

// R6 merged kernel regressed 3x: __threadfence() on gfx950 = per-XCD L2
// writeback/invalidate (cross-XCD coherence), and we issued ~1500 of them
// while 43 MB of output writes sat dirty in L2 -> TCC maintenance storm
// (VALUBusy 12%, 630 GB/s, 115 us). R7: SAME single-kernel overlap, but
// FENCE-FREE handoff: all cross-block data moves via device-scope atomics
// (coherent at device point, no L2 flush); per-wave ordering between
// "data atomic" and "done-counter atomic" enforced by consuming the
// returned value (forces s_waitcnt vmcnt(0) - wave-local, cheap).
// partials[] eliminated: dense blocks atomicAdd noobj straight into acc[0].
#define TP 104
#define TF4 26
#define NF4 2210           // CH * TF4 f4-elements per tile
#define LSTR 105
#define LDSW 8945          // SW(84,103)+1 words = 35.8 KB -> 4 blk/CU
#define NDENSE 1248        // 26 chunks * 48 (B*A)

// Block-id map: 0 = prep; 1..64 = winner gather (4 winners/blk, 1/wave);
// 65..67 = zero-cell corrections (256 idx/blk, 768 total); 68..1315 = dense.
// Last block to bump the done counter finalizes the scalar.
#define PREP_BID 0
#define WIN_B0 1
#define NWINB 64
#define ZERO_B0 (WIN_B0 + NWINB)      // 65
#define NZEROB 3
#define DENSE_B0 (ZERO_B0 + NZEROB)   // 68
#define GRID (DENSE_B0 + NDENSE)      // 1316 (= total done-counter parts)

#define SW(c, l) ((c) * LSTR + (l) + ((c) >> 2))

__device__ __forceinline__ float sigm(float z) { return 1.0f / (1.0f + expf(-z)); }
// -log(sigmoid(z)) = log1p(exp(-z));  -log(1-sigmoid(z)) = log1p(exp(z))
__device__ __forceinline__ float splus(float z) { return log1pf(expf(z)); }

// ws layout (bytes):
//   0    : float acc[16]  acc[0]=dense noobj, acc[1]=obj xywh+conf,
//                         acc[2]=cls, acc[3]=zeroed-cell noobj correction
//   64   : int cnts[8]    {wcount, zcount, unused, done, prep_flag}
//   128  : int   wofs[256]
//   1152 : float wtx[256]
//   2176 : float wty[256]
//   3200 : float wtw[256]
//   4224 : float wth[256]
//   5248 : int   wlabel[256]
//   6272 : int   zofs[768]
// bytes [0,96) zeroed by hipMemsetAsync before the kernel.

__device__ __forceinline__ void finalize(float* acc, int* cnts,
                                         float* out_total) {
    float a0 = atomicAdd(&acc[0], 0.0f);   // coherent reads
    float a1 = atomicAdd(&acc[1], 0.0f);
    float a2 = atomicAdd(&acc[2], 0.0f);
    float a3 = atomicAdd(&acc[3], 0.0f);
    float wc = (float)atomicAdd(&cnts[0], 0);
    float zc = (float)atomicAdd(&cnts[1], 0);
    float n_obj = fmaxf(wc, 1.0f);
    float n_noobj = fmaxf((float)NCELLS - zc, 1.0f);
    float cls_den = fmaxf(80.0f * wc, 1.0f);
    out_total[0] = a1 / n_obj + a2 / cls_den + 0.5f * ((a0 - a3) / n_noobj);
}

__global__ __launch_bounds__(256) void yolo_fused(
        const float* __restrict__ x, float* __restrict__ out,
        const float* __restrict__ target, float* acc,
        int* cnts, int* wofs,
        float* wtx, float* wty,
        float* wtw, float* wth,
        int* wlabel, int* zofs,
        float* __restrict__ out_total) {
    __shared__ float lds[LDSW];        // prep block aliases it (17.3 KB used)
    __shared__ float red[4];
    __shared__ int s_wv[2];
    int bid = blockIdx.x;
    int t = threadIdx.x;

    if (bid == PREP_BID) {
        // ---------------- prep block ----------------
        unsigned int* bm = (unsigned int*)lds;          // [NBMW]
        int* s_keyobj = (int*)lds + NBMW;               // [256]
        int* s_cnt = (int*)lds + NBMW + NT;             // {wcnt, zcnt}
        if (t == 0) { s_cnt[0] = 0; s_cnt[1] = 0; }
        for (int i = t; i < NBMW; i += 256) bm[i] = 0u;

        const float awc[3] = {10.f, 16.f, 33.f};
        const float ahc[3] = {13.f, 30.f, 23.f};
        float timg = target[t*6 + 0];
        float gxc  = target[t*6 + 1] * (float)WW;
        float gyc  = target[t*6 + 2] * (float)HH;
        float gw   = target[t*6 + 3] * (float)WW;
        float gh   = target[t*6 + 4] * (float)HH;
        int label  = (int)target[t*6 + 5];

        float best_iou = -1.0f;
        int best = 0, ignbits = 0;
        for (int a = 0; a < 3; a++) {
            float inter = fminf(awc[a], gw) * fminf(ahc[a], gh);
            float iou = inter / (awc[a]*ahc[a] + 1e-16f + gw*gh - inter);
            if (iou > best_iou) { best_iou = iou; best = a; }  // first-max
            if (iou > IGN_THR) ignbits |= (1 << a);
        }
        int img = (int)timg;
        int gi = (int)gxc, gj = (int)gyc;
        int pixel = gj * WW + gi;
        int cellbase = img * (NA * HW) + pixel;
        int keyobj = cellbase + best * HW;
        s_keyobj[t] = keyobj;
        __syncthreads();

        // winner iff no later target maps to same cell (fixed-trip scan)
        bool dup = false;
        #pragma unroll 8
        for (int m = 0; m < NT; m++) {
            int k = s_keyobj[m];
            dup = dup || (m > t && k == keyobj);
        }
        int sink = 0;
        if (!dup) {
            int p = atomicAdd(&s_cnt[0], 1);
            // publish winner table via device-coherent atomics (no fence)
            sink ^= atomicExch(&wofs[p], (img * NA + best) * (CH * HW) + pixel);
            sink ^= __float_as_int(atomicExch(&wtx[p], gxc - floorf(gxc)));
            sink ^= __float_as_int(atomicExch(&wty[p], gyc - floorf(gyc)));
            sink ^= __float_as_int(atomicExch(&wtw[p], logf(gw / awc[best] + 1e-16f)));
            sink ^= __float_as_int(atomicExch(&wth[p], logf(gh / ahc[best] + 1e-16f)));
            sink ^= atomicExch(&wlabel[p], label);
        }
        // distinct zeroed-noobj cells via bitmap (first setter appends)
        for (int a = 0; a < 3; a++) {
            bool flag = (a == best) || ((ignbits >> a) & 1);
            if (flag) {
                int key = cellbase + a * HW;
                unsigned int bit = 1u << (key & 31);
                unsigned int old = atomicOr(&bm[key >> 5], bit);
                if (!(old & bit)) {
                    int p = atomicAdd(&s_cnt[1], 1);
                    sink ^= atomicExch(&zofs[p],
                                ((img * NA + a) * CH + 4) * HW + pixel);
                }
            }
        }
        asm volatile("" :: "v"(sink) : "memory");  // table exchanges complete
        __syncthreads();
        if (t == 0) {
            int o0 = atomicExch(&cnts[0], s_cnt[0]);
            int o1 = atomicExch(&cnts[1], s_cnt[1]);
            asm volatile("" :: "v"(o0), "v"(o1) : "memory");
            int of = atomicExch(&cnts[4], 1);      // publish: prep ready
            asm volatile("" :: "v"(of) : "memory");
            int o = atomicAdd(&cnts[3], 1);
            if (o == GRID - 1) finalize(acc, cnts, out_total);
        }
        return;
    }

    if (bid >= DENSE_B0) {
        // ---------------- dense transform block ----------------
        int dbid  = bid - DENSE_B0;
        int chunk = dbid % 26;           // pixel chunk (104 px = 2 grid rows)
        int ba    = dbid / 26;           // b*3 + a
        int a     = ba % NA;
        const float awc[3] = {10.f, 16.f, 33.f};
        const float ahc[3] = {13.f, 30.f, 23.f};

        // Phase 1: batched float4 loads, then transform -> swizzled LDS
        const float4* x4 = (const float4*)x + (size_t)ba * (CH * HWF4)
                                            + chunk * TF4;
        float4 v[9];
        #pragma unroll
        for (int i = 0; i < 9; i++) {
            int idx = t + i * 256;
            if (idx < NF4) {
                int c = idx / TF4, q = idx - c * TF4;
                v[i] = x4[c * HWF4 + q];
            }
        }
        float noobj = 0.0f;
        #pragma unroll
        for (int i = 0; i < 9; i++) {
            int idx = t + i * 256;
            if (idx < NF4) {
                int c = idx / TF4, q = idx - c * TF4;
                float r[4] = {v[i].x, v[i].y, v[i].z, v[i].w};
                #pragma unroll
                for (int k = 0; k < 4; k++) {
                    int l = q * 4 + k;               // local pixel 0..103
                    float z = r[k], o;
                    if (c == 0) {
                        int wc = l - ((l >= WW) ? WW : 0);
                        o = (sigm(z) + (float)wc) * STRIDE_F;
                    } else if (c == 1) {
                        int hc = chunk * 2 + ((l >= WW) ? 1 : 0);
                        o = (sigm(z) + (float)hc) * STRIDE_F;
                    } else if (c == 2) {
                        o = expf(z) * awc[a];
                    } else if (c == 3) {
                        o = expf(z) * ahc[a];
                    } else {
                        o = sigm(z);
                        if (c == 4) noobj += splus(z);
                    }
                    lds[SW(c, l)] = o;
                }
            }
        }
        // reduce noobj partial across the block
        for (int off = 32; off > 0; off >>= 1)
            noobj += __shfl_down(noobj, off, 64);
        if ((t & 63) == 0) red[t >> 6] = noobj;
        __syncthreads();

        // Phase 2: float4 stores of [cell][channel]-ordered output
        float4* o4 = (float4*)out + (size_t)ba * (HW * CH / 4) + chunk * NF4;
        #pragma unroll
        for (int i = 0; i < 9; i++) {
            int j = t + i * 256;
            if (j < NF4) {
                int flat = 4 * j;
                int cell = flat / CH;            // local cell 0..103
                int ch = flat - cell * CH;
                float4 w;
                float* pw = &w.x;
                #pragma unroll
                for (int k = 0; k < 4; k++) {
                    int chk = ch + k, cek = cell;
                    if (chk >= CH) { chk -= CH; cek += 1; }
                    pw[k] = lds[SW(chk, cek)];
                }
                o4[j] = w;
            }
        }
        if (t == 0) {
            float p = red[0] + red[1] + red[2] + red[3];
            float old = atomicAdd(&acc[0], p);     // direct to accumulator
            asm volatile("" :: "v"(old) : "memory");  // add complete @ device
            int o = atomicAdd(&cnts[3], 1);
            if (o == GRID - 1) finalize(acc, cnts, out_total);
        }
        return;
    }

    // ---------------- tail blocks: wait for prep publish ----------------
    if (t == 0) {
        while (atomicAdd(&cnts[4], 0) == 0)
            __builtin_amdgcn_s_sleep(8);
        s_wv[0] = atomicAdd(&cnts[0], 0);          // wcount
        s_wv[1] = atomicAdd(&cnts[1], 0);          // zcount
    }
    __syncthreads();

    if (bid < ZERO_B0) {
        // ---- winner gather: one winner per 64-lane wave ----
        int wave = t >> 6, lane = t & 63;
        int w = (bid - WIN_B0) * 4 + wave;
        if (w < s_wv[0]) {
            int ofs = 0, label = 0;
            float ttx = 0.f, tty = 0.f, ttw = 0.f, tth = 0.f;
            if (lane == 0) {                       // coherent table reads
                ofs   = atomicAdd(&wofs[w], 0);
                label = atomicAdd(&wlabel[w], 0);
                ttx = atomicAdd(&wtx[w], 0.0f);
                tty = atomicAdd(&wty[w], 0.0f);
                ttw = atomicAdd(&wtw[w], 0.0f);
                tth = atomicAdd(&wth[w], 0.0f);
            }
            ofs   = __shfl(ofs, 0, 64);
            label = __shfl(label, 0, 64);
            const float* xp = x + ofs;
            float lcls;
            {   // class channels 0..63
                float z = xp[(size_t)(5 + lane) * HW];
                lcls = (lane == label) ? splus(-z) : splus(z);
            }
            if (lane < 16) {               // class channels 64..79
                int c = 64 + lane;
                float z = xp[(size_t)(5 + c) * HW];
                lcls += (c == label) ? splus(-z) : splus(z);
            }
            float other = 0.0f;
            if (lane == 0) {
                float z0 = xp[0];
                float z2 = xp[(size_t)2 * HW];
                float z4 = xp[(size_t)4 * HW];
                float cx = sigm(z0);
                float dx = cx - ttx, dy = cx - tty;   // ref bug: cx for y
                float dw = z2 - ttw, dh = z2 - tth;   // ref bug: pw for h
                other = dx*dx + dy*dy + dw*dw + dh*dh + splus(-z4);
            }
            for (int off = 32; off > 0; off >>= 1)
                lcls += __shfl_down(lcls, off, 64);
            if (lane == 0) {
                float o1 = atomicAdd(&acc[1], other);
                float o2 = atomicAdd(&acc[2], lcls);
                asm volatile("" :: "v"(o1), "v"(o2) : "memory");
            }
        }
    } else {
        // ---- zero-cell noobj corrections (768 slots over 3 blocks) ----
        int idx = (bid - ZERO_B0) * 256 + t;
        float vv = 0.0f;
        if (idx < s_wv[1]) {
            int z = atomicAdd(&zofs[idx], 0);      // coherent read
            vv = splus(x[z]);
        }
        for (int off = 32; off > 0; off >>= 1)
            vv += __shfl_down(vv, off, 64);
        if ((t & 63) == 0) {
            float o3 = atomicAdd(&acc[3], vv);
            asm volatile("" :: "v"(o3) : "memory");
        }
    }

    // block-level completion: all waves' acc adds done (syncthreads drains
    // vmcnt per wave; each wave consumed its atomic returns above)
    __syncthreads();
    if (t == 0) {
        int o = atomicAdd(&cnts[3], 1);
        if (o == GRID - 1) finalize(acc, cnts, out_total);
    }
}

// ---------------------------------------------------------------------------
extern "C" void kernel_launch(void* const* d_in, const int* in_sizes, int n_in,
                              void* d_out, int out_size, void* d_ws, size_t ws_size,
                              hipStream_t stream) {
    (void)in_sizes; (void)n_in; (void)out_size; (void)ws_size;
    const float* x      = (const float*)d_in[0];
    const float* target = (const float*)d_in[1];
    float* out = (float*)d_out;

    char* ws = (char*)d_ws;
    float* acc      = (float*)(ws + 0);
    int*   cnts     = (int*)  (ws + 64);
    int*   wofs     = (int*)  (ws + 128);
    float* wtx      = (float*)(ws + 1152);
    float* wty      = (float*)(ws + 2176);
    float* wtw      = (float*)(ws + 3200);
    float* wth      = (float*)(ws + 4224);
    int*   wlabel   = (int*)  (ws + 5248);
    int*   zofs     = (int*)  (ws + 6272);

    // zero acc[16] + cnts[8] (workspace is poisoned between iterations)
    hipMemsetAsync(ws, 0, 96, stream);
    yolo_fused<<<GRID, 256, 0, stream>>>(
        x, out, target, acc, cnts, wofs, wtx, wty, wtw, wth, wlabel, zofs,
        out + (size_t)NB * NA * HW * CH);
}

// Round 3
// 124.195 us; speedup vs baseline: 1.4921x; 1.3098x over previous
//
#include <hip/hip_runtime.h>
#include <math.h>

// Problem constants (from reference)
#define NA 3
#define NC 80
#define CH 85              // NC+5
#define NB 16
#define HH 52
#define WW 52
#define HW 2704            // HH*WW
#define HWF4 676           // HW/4
#define NT 256             // num targets
#define NCELLS (NB*NA*HW)  // 129792
#define NBMW 4056          // bitmap words = ceil(NCELLS/32)
#define STRIDE_F 8.0f      // 416/52
#define IGN_THR 0.5f

// R6/R7 lesson: in-kernel cross-block sync (fences OR spin+atomic handoff)
// taxed the whole dispatch 2-3x vs the plain dense kernel. R8: overlap via
// KERNEL BOUNDARIES only. A: prep (tables via plain stores, zeroes acc).
// B: tail blocks (low bids, read A's tables plainly -- coherent across the
// launch boundary) overlap with dense blocks (identical to round-0 fast
// path, plain partials[] store, zero atomics); tail folds into acc[1..3]
// with fire-and-forget atomicAdd (return unused -> no wait).
// C: sums partials + acc, writes scalar. No fence, no spin, no done counter.
#define TP 104
#define TF4 26
#define NF4 2210           // CH * TF4 f4-elements per tile
#define LSTR 105
#define LDSW 8945          // SW(84,103)+1 words = 35.8 KB -> 4 blk/CU
#define NDENSE 1248        // 26 chunks * 48 (B*A)

// Kernel-B block map: 0..63 winner gather (4 winners/blk, 1/wave);
// 64..66 zero-cell corrections (256 idx/blk); 67..1314 dense.
#define NWINB 64
#define NZEROB 3
#define TAILB (NWINB + NZEROB)        // 67
#define GRID_B (TAILB + NDENSE)       // 1315

#define SW(c, l) ((c) * LSTR + (l) + ((c) >> 2))

__device__ __forceinline__ float sigm(float z) { return 1.0f / (1.0f + expf(-z)); }
// -log(sigmoid(z)) = log1p(exp(-z));  -log(1-sigmoid(z)) = log1p(exp(z))
__device__ __forceinline__ float splus(float z) { return log1pf(expf(z)); }

// ws layout (bytes):
//   0    : float acc[16]  acc[1]=obj xywh+conf, acc[2]=cls, acc[3]=zero-cell
//   64   : int cnts[8]    {wcount, zcount}
//   128  : int   wofs[256]
//   1152 : float wtx[256]
//   2176 : float wty[256]
//   3200 : float wtw[256]
//   4224 : float wth[256]
//   5248 : int   wlabel[256]
//   6272 : int   zofs[768]
//   9344 : float partials[1248]
// All zeroing/coherence handled by kernel A + launch boundaries.

// ---------------------------------------------------------------------------
// Kernel A: target prep (1 block, 256 threads). Plain stores only.
// ---------------------------------------------------------------------------
__global__ __launch_bounds__(256) void prep_kernel(
        const float* __restrict__ target, float* __restrict__ acc,
        int* __restrict__ cnts, int* __restrict__ wofs,
        float* __restrict__ wtx, float* __restrict__ wty,
        float* __restrict__ wtw, float* __restrict__ wth,
        int* __restrict__ wlabel, int* __restrict__ zofs) {
    __shared__ int plds[NBMW + NT + 2];
    unsigned int* bm = (unsigned int*)plds;     // [NBMW]
    int* s_keyobj = plds + NBMW;                // [256]
    int* s_cnt = plds + NBMW + NT;              // {wcnt, zcnt}
    int t = threadIdx.x;

    if (t < 16) acc[t] = 0.0f;                  // zero accumulators
    if (t == 0) { s_cnt[0] = 0; s_cnt[1] = 0; }
    for (int i = t; i < NBMW; i += 256) bm[i] = 0u;

    const float awc[3] = {10.f, 16.f, 33.f};
    const float ahc[3] = {13.f, 30.f, 23.f};
    float timg = target[t*6 + 0];
    float gxc  = target[t*6 + 1] * (float)WW;
    float gyc  = target[t*6 + 2] * (float)HH;
    float gw   = target[t*6 + 3] * (float)WW;
    float gh   = target[t*6 + 4] * (float)HH;
    int label  = (int)target[t*6 + 5];

    float best_iou = -1.0f;
    int best = 0, ignbits = 0;
    for (int a = 0; a < 3; a++) {
        float inter = fminf(awc[a], gw) * fminf(ahc[a], gh);
        float iou = inter / (awc[a]*ahc[a] + 1e-16f + gw*gh - inter);
        if (iou > best_iou) { best_iou = iou; best = a; }  // first-max
        if (iou > IGN_THR) ignbits |= (1 << a);
    }
    int img = (int)timg;
    int gi = (int)gxc, gj = (int)gyc;
    int pixel = gj * WW + gi;
    int cellbase = img * (NA * HW) + pixel;
    int keyobj = cellbase + best * HW;
    s_keyobj[t] = keyobj;
    __syncthreads();

    // winner iff no later target maps to same cell (fixed-trip scan)
    bool dup = false;
    #pragma unroll 8
    for (int m = 0; m < NT; m++) {
        int k = s_keyobj[m];
        dup = dup || (m > t && k == keyobj);
    }
    if (!dup) {
        int p = atomicAdd(&s_cnt[0], 1);
        wofs[p] = (img * NA + best) * (CH * HW) + pixel;
        wtx[p] = gxc - floorf(gxc);
        wty[p] = gyc - floorf(gyc);
        wtw[p] = logf(gw / awc[best] + 1e-16f);
        wth[p] = logf(gh / ahc[best] + 1e-16f);
        wlabel[p] = label;
    }
    // distinct zeroed-noobj cells via bitmap (first setter appends)
    for (int a = 0; a < 3; a++) {
        bool flag = (a == best) || ((ignbits >> a) & 1);
        if (flag) {
            int key = cellbase + a * HW;
            unsigned int bit = 1u << (key & 31);
            unsigned int old = atomicOr(&bm[key >> 5], bit);
            if (!(old & bit)) {
                int p = atomicAdd(&s_cnt[1], 1);
                zofs[p] = ((img * NA + a) * CH + 4) * HW + pixel;
            }
        }
    }
    __syncthreads();
    if (t == 0) { cnts[0] = s_cnt[0]; cnts[1] = s_cnt[1]; }
    // kernel boundary provides coherence to kernel B
}

// ---------------------------------------------------------------------------
// Kernel B: tail blocks (0..66) overlap with dense blocks (67..1314).
// ---------------------------------------------------------------------------
__global__ __launch_bounds__(256) void main_kernel(
        const float* __restrict__ x, float* __restrict__ out,
        float* __restrict__ acc, const int* __restrict__ cnts,
        const int* __restrict__ wofs, const float* __restrict__ wtx,
        const float* __restrict__ wty, const float* __restrict__ wtw,
        const float* __restrict__ wth, const int* __restrict__ wlabel,
        const int* __restrict__ zofs, float* __restrict__ partials) {
    __shared__ float lds[LDSW];
    __shared__ float red[4];
    int bid = blockIdx.x;
    int t = threadIdx.x;

    if (bid >= TAILB) {
        // ---------------- dense transform block (round-0 fast path) -------
        int dbid  = bid - TAILB;
        int chunk = dbid % 26;           // pixel chunk (104 px = 2 grid rows)
        int ba    = dbid / 26;           // b*3 + a
        int a     = ba % NA;
        const float awc[3] = {10.f, 16.f, 33.f};
        const float ahc[3] = {13.f, 30.f, 23.f};

        // Phase 1: batched float4 loads, then transform -> swizzled LDS
        const float4* x4 = (const float4*)x + (size_t)ba * (CH * HWF4)
                                            + chunk * TF4;
        float4 v[9];
        #pragma unroll
        for (int i = 0; i < 9; i++) {
            int idx = t + i * 256;
            if (idx < NF4) {
                int c = idx / TF4, q = idx - c * TF4;
                v[i] = x4[c * HWF4 + q];
            }
        }
        float noobj = 0.0f;
        #pragma unroll
        for (int i = 0; i < 9; i++) {
            int idx = t + i * 256;
            if (idx < NF4) {
                int c = idx / TF4, q = idx - c * TF4;
                float r[4] = {v[i].x, v[i].y, v[i].z, v[i].w};
                #pragma unroll
                for (int k = 0; k < 4; k++) {
                    int l = q * 4 + k;               // local pixel 0..103
                    float z = r[k], o;
                    if (c == 0) {
                        int wc = l - ((l >= WW) ? WW : 0);
                        o = (sigm(z) + (float)wc) * STRIDE_F;
                    } else if (c == 1) {
                        int hc = chunk * 2 + ((l >= WW) ? 1 : 0);
                        o = (sigm(z) + (float)hc) * STRIDE_F;
                    } else if (c == 2) {
                        o = expf(z) * awc[a];
                    } else if (c == 3) {
                        o = expf(z) * ahc[a];
                    } else {
                        o = sigm(z);
                        if (c == 4) noobj += splus(z);
                    }
                    lds[SW(c, l)] = o;
                }
            }
        }
        // reduce noobj partial across the block
        for (int off = 32; off > 0; off >>= 1)
            noobj += __shfl_down(noobj, off, 64);
        if ((t & 63) == 0) red[t >> 6] = noobj;
        __syncthreads();

        // Phase 2: float4 stores of [cell][channel]-ordered output
        float4* o4 = (float4*)out + (size_t)ba * (HW * CH / 4) + chunk * NF4;
        #pragma unroll
        for (int i = 0; i < 9; i++) {
            int j = t + i * 256;
            if (j < NF4) {
                int flat = 4 * j;
                int cell = flat / CH;            // local cell 0..103
                int ch = flat - cell * CH;
                float4 w;
                float* pw = &w.x;
                #pragma unroll
                for (int k = 0; k < 4; k++) {
                    int chk = ch + k, cek = cell;
                    if (chk >= CH) { chk -= CH; cek += 1; }
                    pw[k] = lds[SW(chk, cek)];
                }
                o4[j] = w;
            }
        }
        if (t == 0) partials[dbid] = red[0] + red[1] + red[2] + red[3];
        return;
    }

    if (bid < NWINB) {
        // ---- winner gather: one winner per 64-lane wave (4 per block) ----
        int wave = t >> 6, lane = t & 63;
        int w = bid * 4 + wave;
        if (w < cnts[0]) {
            int ofs = wofs[w];               // plain loads: coherent via
            int label = wlabel[w];           // the A->B launch boundary
            const float* xp = x + ofs;
            float lcls;
            {   // class channels 0..63
                float z = xp[(size_t)(5 + lane) * HW];
                lcls = (lane == label) ? splus(-z) : splus(z);
            }
            if (lane < 16) {                 // class channels 64..79
                int c = 64 + lane;
                float z = xp[(size_t)(5 + c) * HW];
                lcls += (c == label) ? splus(-z) : splus(z);
            }
            float other = 0.0f;
            if (lane == 0) {
                float z0 = xp[0];
                float z2 = xp[(size_t)2 * HW];
                float z4 = xp[(size_t)4 * HW];
                float cx = sigm(z0);
                float dx = cx - wtx[w], dy = cx - wty[w];  // ref bug: cx for y
                float dw = z2 - wtw[w], dh = z2 - wth[w];  // ref bug: pw for h
                other = dx*dx + dy*dy + dw*dw + dh*dh + splus(-z4);
            }
            for (int off = 32; off > 0; off >>= 1)
                lcls += __shfl_down(lcls, off, 64);
            if (lane == 0) {
                atomicAdd(&acc[1], other);   // fire-and-forget (no return use)
                atomicAdd(&acc[2], lcls);
            }
        }
    } else {
        // ---- zero-cell noobj corrections (768 slots over 3 blocks) ----
        int idx = (bid - NWINB) * 256 + t;
        float vv = 0.0f;
        if (idx < cnts[1]) vv = splus(x[zofs[idx]]);
        for (int off = 32; off > 0; off >>= 1)
            vv += __shfl_down(vv, off, 64);
        if ((t & 63) == 0) atomicAdd(&acc[3], vv);   // fire-and-forget
    }
}

// ---------------------------------------------------------------------------
// Kernel C: finalize (1 block). Reads everything across the B->C boundary.
// ---------------------------------------------------------------------------
__global__ __launch_bounds__(256) void finalize_kernel(
        const float* __restrict__ partials, const float* __restrict__ acc,
        const int* __restrict__ cnts, float* __restrict__ out_total) {
    __shared__ float red[4];
    int t = threadIdx.x;
    float s = 0.0f;
    for (int i = t; i < NDENSE; i += 256) s += partials[i];
    for (int off = 32; off > 0; off >>= 1)
        s += __shfl_down(s, off, 64);
    if ((t & 63) == 0) red[t >> 6] = s;
    __syncthreads();
    if (t == 0) {
        float a0 = red[0] + red[1] + red[2] + red[3];   // dense noobj sum
        float a1 = acc[1], a2 = acc[2], a3 = acc[3];
        float wc = (float)cnts[0];
        float zc = (float)cnts[1];
        float n_obj = fmaxf(wc, 1.0f);
        float n_noobj = fmaxf((float)NCELLS - zc, 1.0f);
        float cls_den = fmaxf(80.0f * wc, 1.0f);
        out_total[0] = a1 / n_obj + a2 / cls_den
                     + 0.5f * ((a0 - a3) / n_noobj);
    }
}

// ---------------------------------------------------------------------------
extern "C" void kernel_launch(void* const* d_in, const int* in_sizes, int n_in,
                              void* d_out, int out_size, void* d_ws, size_t ws_size,
                              hipStream_t stream) {
    (void)in_sizes; (void)n_in; (void)out_size; (void)ws_size;
    const float* x      = (const float*)d_in[0];
    const float* target = (const float*)d_in[1];
    float* out = (float*)d_out;

    char* ws = (char*)d_ws;
    float* acc      = (float*)(ws + 0);
    int*   cnts     = (int*)  (ws + 64);
    int*   wofs     = (int*)  (ws + 128);
    float* wtx      = (float*)(ws + 1152);
    float* wty      = (float*)(ws + 2176);
    float* wtw      = (float*)(ws + 3200);
    float* wth      = (float*)(ws + 4224);
    int*   wlabel   = (int*)  (ws + 5248);
    int*   zofs     = (int*)  (ws + 6272);
    float* partials = (float*)(ws + 9344);

    prep_kernel<<<1, 256, 0, stream>>>(
        target, acc, cnts, wofs, wtx, wty, wtw, wth, wlabel, zofs);
    main_kernel<<<GRID_B, 256, 0, stream>>>(
        x, out, acc, cnts, wofs, wtx, wty, wtw, wth, wlabel, zofs, partials);
    finalize_kernel<<<1, 256, 0, stream>>>(
        partials, acc, cnts, out + (size_t)NB * NA * HW * CH);
}